// Round 7
// baseline (282.764 us; speedup 1.0000x reference)
//
#include <hip/hip_runtime.h>
#include <hip/hip_bf16.h>
#include <stdint.h>

typedef __attribute__((ext_vector_type(4))) float f32x4;
typedef __attribute__((ext_vector_type(8))) __bf16 bf16x8;
typedef unsigned short u16;
typedef unsigned long long u64;

__device__ __forceinline__ u16 f2bf(float f){
  unsigned u = __float_as_uint(f);
  u += 0x7fffu + ((u >> 16) & 1u);
  return (u16)(u >> 16);
}
__device__ __forceinline__ float bf2f(u16 v){
  return __uint_as_float(((unsigned)v) << 16);
}

__device__ __forceinline__ void gload16(const u16* g, u16* l){
  __builtin_amdgcn_global_load_lds(
      (__attribute__((address_space(1))) void*)g,
      (__attribute__((address_space(3))) void*)l, 16, 0, 0);
}

template<int N> __device__ __forceinline__ void waitcnt_vm(){
  if constexpr (N==0)  asm volatile("s_waitcnt vmcnt(0)" ::: "memory");
  else if constexpr (N==4)  asm volatile("s_waitcnt vmcnt(4)" ::: "memory");
  else if constexpr (N==6)  asm volatile("s_waitcnt vmcnt(6)" ::: "memory");
  else if constexpr (N==8)  asm volatile("s_waitcnt vmcnt(8)" ::: "memory");
  else if constexpr (N==12) asm volatile("s_waitcnt vmcnt(12)" ::: "memory");
}

// ---- fp32 row matrix -> bf16 copy + numpy-pairwise row sum-of-squares ----
__global__ __launch_bounds__(64)
void cvt_rows(const float* __restrict__ src, u16* __restrict__ dst,
              float* __restrict__ sq)
{
#pragma clang fp contract(off)
  const int row = blockIdx.x;
  const int l = threadIdx.x;
  const float* r = src + (size_t)row * 2048;
  const f32x4* r4 = (const f32x4*)r;
  ushort4* d4 = (ushort4*)(dst + (size_t)row * 2048);
#pragma unroll
  for (int i = 0; i < 8; i++){
    f32x4 v = r4[l + 64*i];
    ushort4 o;
    o.x = f2bf(v.x); o.y = f2bf(v.y); o.z = f2bf(v.z); o.w = f2bf(v.w);
    d4[l + 64*i] = o;
  }
  float leaf = 0.f;
  if (l < 16){
    const f32x4* p4 = (const f32x4*)(r + l*128);
    f32x4 a0 = {0.f,0.f,0.f,0.f}, a1 = {0.f,0.f,0.f,0.f};
#pragma unroll
    for (int i = 0; i < 32; i += 2){
      f32x4 v0 = p4[i], v1 = p4[i+1];
      a0 = a0 + v0*v0;
      a1 = a1 + v1*v1;
    }
    leaf = ((a0.x+a0.y)+(a0.z+a0.w))+((a1.x+a1.y)+(a1.z+a1.w));
  }
#pragma unroll
  for (int s = 1; s < 16; s <<= 1){
    float o = __shfl_down(leaf, s);
    if ((l & (2*s - 1)) == 0) leaf = leaf + o;
  }
  if (l == 0) sq[row] = leaf;
}

// ---- generic fp32 -> bf16 elementwise ----
__global__ __launch_bounds__(256)
void cvt_mat(const float* __restrict__ src, u16* __restrict__ dst, int n4)
{
  const f32x4* s4 = (const f32x4*)src;
  ushort4* d4 = (ushort4*)dst;
  for (int i = blockIdx.x*256 + threadIdx.x; i < n4; i += gridDim.x*256){
    f32x4 v = s4[i];
    ushort4 o;
    o.x = f2bf(v.x); o.y = f2bf(v.y); o.z = f2bf(v.z); o.w = f2bf(v.w);
    d4[i] = o;
  }
}

// ==== gemmA: 256x128 BK=32 bf16 GEMM, 4 waves, 2 blocks/CU ====
// Mechanism: two INDEPENDENT workgroups per CU provide the LDS<->MFMA
// overlap that barrier-locked waves cannot (m97/m114 implicit overlap).
// 3 LDS K-tile buffers (72KB), stage t+2 ahead, ONE barrier per K-tile.
// Race-freedom (rendezvous-only): stage(t+2) overwrites buf[(t-1)%3];
// every wave's reads of buf[t-1] were consumed by its own MFMAs in
// section t-1 (compiler lgkmcnt before use), hence delivered before that
// wave reached end-barrier(t-1); stage(t+2) is issued after this wave
// crossed end-barrier(t-1+1)... i.e. strictly after all waves crossed
// end-barrier(t-1). vmcnt(6) at tile end: leaves exactly stage(t+2) in
// flight, forces stage(t+1) landed; barrier publishes it.
// Swizzle (proven r3, conflicts=0): read chunk' = fq ^ ((fr>>1)&3);
// stage source col pre-swizzled so global_load_lds stays linear.
// Epilogue: per-wave 128x64 patch in LDS with 136B row stride
// (banks = 2*row + col/2 : conflict-free), 16B coalesced global stores.
__global__ __launch_bounds__(256, 2)
void gemmA(const u16* __restrict__ A, int lda,
           const u16* __restrict__ Bm, int ldb,
           u16* __restrict__ Cb, int N, int Kpp, int nbn, int blkpp)
{
  constexpr int BUFB = 24576;            // (256+128)*32*2
  constexpr int ABYTES = 16384;          // 256*32*2
  extern __shared__ char lds[];
  const int t = threadIdx.x;
  const int nwg = gridDim.x;
  const int cpx = nwg >> 3;
  const int bid = blockIdx.x;
  const int wg  = (bid & 7)*cpx + (bid >> 3);   // XCD swizzle (nwg%8==0)
  const int piece = wg / blkpp;
  const int rem = wg % blkpp;
  const int bm = rem / nbn, bn = rem % nbn;
  const int brow = bm*256, bcol = bn*128;
  const u16* Ab = A + (size_t)brow*lda + (size_t)piece*Kpp;
  const u16* Bb = Bm + (size_t)bcol*ldb + (size_t)piece*Kpp;
  u16* Cp = Cb + (size_t)piece * 4096 * N;

  const int l = t & 63, w = t >> 6;
  const int wm = w >> 1, wn = w & 1;
  const int wr = wm*128, wc = wn*64;
  const int fr = l & 15, fq = l >> 4;
  const int xk = (fq ^ ((fr >> 1) & 3))*8;       // swizzled chunk (u16)

  const int srow = t >> 2;
  const int scol = ((t & 3) ^ ((t >> 3) & 3))*8; // inverse-swz source col

  const u16* agp[4]; const u16* bgp[2];
#pragma unroll
  for (int r = 0; r < 4; r++)
    agp[r] = Ab + (size_t)(r*64 + srow)*lda + scol;
#pragma unroll
  for (int r = 0; r < 2; r++)
    bgp[r] = Bb + (size_t)(r*64 + srow)*ldb + scol;

  f32x4 acc[8][4] = {};
  const int nt = Kpp >> 5;

  auto stage = [&](int kt, int buf){
    char* dst = lds + buf*BUFB + t*16;
#pragma unroll
    for (int r = 0; r < 4; r++)
      gload16(agp[r] + (kt << 5), (u16*)(dst + r*4096));
#pragma unroll
    for (int r = 0; r < 2; r++)
      gload16(bgp[r] + (kt << 5), (u16*)(dst + ABYTES + r*4096));
  };

  stage(0, 0); stage(1, 1); stage(2, 2);
  waitcnt_vm<12>();
  __builtin_amdgcn_s_barrier();

  int buf = 0;
  for (int kt = 0; kt < nt; kt++){
    const u16* As = (const u16*)(lds + buf*BUFB);
    const u16* Bs = (const u16*)(lds + buf*BUFB + ABYTES);
    const int nbuf = (buf + 2 < 3) ? buf + 2 : buf - 1;

    bf16x8 av[8], bv[4];
#pragma unroll
    for (int m = 0; m < 8; m++)
      av[m] = *(const bf16x8*)(As + (wr + m*16 + fr)*32 + xk);
#pragma unroll
    for (int n = 0; n < 4; n++)
      bv[n] = *(const bf16x8*)(Bs + (wc + n*16 + fr)*32 + xk);
    if (kt + 2 < nt) stage(kt + 2, nbuf);
    __builtin_amdgcn_s_setprio(1);
#pragma unroll
    for (int m = 0; m < 8; m++)
#pragma unroll
      for (int n = 0; n < 4; n++)
        acc[m][n] = __builtin_amdgcn_mfma_f32_16x16x32_bf16(av[m], bv[n], acc[m][n], 0, 0, 0);
    __builtin_amdgcn_s_setprio(0);

    if (kt + 1 < nt){
      if (kt + 2 < nt) waitcnt_vm<6>();
      else             waitcnt_vm<0>();
      __builtin_amdgcn_s_barrier();
    }
    buf = (buf + 1 < 3) ? buf + 1 : 0;
  }

  // ---- epilogue: LDS transpose (136B row stride, conflict-free) ----
  __builtin_amdgcn_s_barrier();
  u16* ep = (u16*)(lds + w*17408);       // 128 rows x 68 u16
#pragma unroll
  for (int m = 0; m < 8; m++)
#pragma unroll
    for (int n = 0; n < 4; n++)
#pragma unroll
      for (int r = 0; r < 4; r++)
        ep[(m*16 + fq*4 + r)*68 + n*16 + fr] = f2bf(acc[m][n][r]);
  asm volatile("s_waitcnt lgkmcnt(0)" ::: "memory");
  const int erow = l >> 3, ecb = (l & 7)*16;
#pragma unroll
  for (int it = 0; it < 16; it++){
    const int row = it*8 + erow;
    f32x4 v = *(const f32x4*)((const char*)ep + row*136 + ecb);
    char* gp = (char*)Cp + (((size_t)(brow + wr + row))*N + (bcol + wc))*2 + ecb;
    *(f32x4*)gp = v;
  }
}

// ---- combine split-K partials + bias + relu -> bf16 ----
__global__ __launch_bounds__(256)
void combine_relu(const u16* __restrict__ p0, const u16* __restrict__ p1,
                  const float* __restrict__ bias, u16* __restrict__ out)
{
  const int n4 = 4096*2048/4;
  for (int i = blockIdx.x*256 + threadIdx.x; i < n4; i += gridDim.x*256){
    ushort4 a = ((const ushort4*)p0)[i];
    ushort4 b = ((const ushort4*)p1)[i];
    const int col = (i*4) & 2047;
    f32x4 bi = *(const f32x4*)(bias + col);
    ushort4 o;
    o.x = f2bf(fmaxf(bf2f(a.x) + bf2f(b.x) + bi.x, 0.f));
    o.y = f2bf(fmaxf(bf2f(a.y) + bf2f(b.y) + bi.y, 0.f));
    o.z = f2bf(fmaxf(bf2f(a.z) + bf2f(b.z) + bi.z, 0.f));
    o.w = f2bf(fmaxf(bf2f(a.w) + bf2f(b.w) + bi.w, 0.f));
    ((ushort4*)out)[i] = o;
  }
}

// ---- small-GEMM pipeline (G3/G4): 1 barrier per K-tile + LDS epilogue ----
template<int BM, int BN, int WM, int WN, int EPI, int MINW>
__global__ __launch_bounds__(WM*WN*64, MINW)
void gemm_p(const u16* __restrict__ A, const u16* __restrict__ Bm,
            float* __restrict__ Cf, u16* __restrict__ Cb,
            const float* __restrict__ bias,
            int M, int N, int K, int ncols, int nbn)
{
  constexpr int T  = WM*WN*64;
  constexpr int FM = BM/(WM*16);
  constexpr int FN = BN/(WN*16);
  constexpr int ABYTES = BM*64;
  constexpr int BUFB   = (BM+BN)*64;
  constexpr int RA = ABYTES/(T*16);
  constexpr int RB = (BN*64)/(T*16);
  extern __shared__ char lds[];

  const int t = threadIdx.x;
  const int nwg = gridDim.x;
  const int cpx = nwg >> 3;
  const int bid = blockIdx.x;
  const int wg  = (bid & 7)*cpx + (bid >> 3);
  const int bm = wg / nbn, bn = wg % nbn;
  const int brow = bm*BM, bcol = bn*BN;

  const int l = t & 63, w = t >> 6;
  const int wm = w / WN, wn = w % WN;
  const int wr = wm*(FM*16), wc = wn*(FN*16);
  const int fr = l & 15, fq = l >> 4, fk = fq*8;
  const int xk = fk ^ (((fr >> 1) & 3) << 3);

  const int srow = t >> 2;
  const int scol = ((t & 3)*8) ^ (((t >> 3) & 3) << 3);

  const u16* agp[RA]; const u16* bgp[RB];
#pragma unroll
  for (int r = 0; r < RA; r++)
    agp[r] = A + (size_t)(brow + r*(T>>2) + srow)*K + scol;
#pragma unroll
  for (int r = 0; r < RB; r++)
    bgp[r] = Bm + (size_t)(bcol + r*(T>>2) + srow)*K + scol;

  f32x4 acc[FM][FN] = {};
  const int nt = K >> 5;

  auto stageA = [&](int kt, int buf){
    char* dst = lds + buf*BUFB + t*16;
#pragma unroll
    for (int r = 0; r < RA; r++)
      gload16(agp[r] + (kt << 5), (u16*)(dst + r*T*16));
  };
  auto stageB = [&](int kt, int buf){
    char* dst = lds + buf*BUFB + ABYTES + t*16;
#pragma unroll
    for (int r = 0; r < RB; r++)
      gload16(bgp[r] + (kt << 5), (u16*)(dst + r*T*16));
  };

  stageA(0, 0); stageB(0, 0);
  stageA(1, 1); stageB(1, 1);
  stageA(2, 2); stageB(2, 2);
  waitcnt_vm<8>();
  __builtin_amdgcn_s_barrier();

  for (int kt = 0; kt < nt; kt++){
    const int buf = kt & 3;
    const u16* As = (const u16*)(lds + buf*BUFB);
    const u16* Bs = (const u16*)(lds + buf*BUFB + ABYTES);
    const bool pre = (kt + 3 < nt);
    const int nbuf = (kt + 3) & 3;

    bf16x8 av[FM], bv[FN];
#pragma unroll
    for (int m = 0; m < FM; m++)
      av[m] = *(const bf16x8*)(As + (wr + m*16 + fr)*32 + xk);
#pragma unroll
    for (int n = 0; n < FN; n++)
      bv[n] = *(const bf16x8*)(Bs + (wc + n*16 + fr)*32 + xk);
    if (pre){ stageA(kt + 3, nbuf); stageB(kt + 3, nbuf); }
    __builtin_amdgcn_s_setprio(1);
#pragma unroll
    for (int m = 0; m < FM; m++)
#pragma unroll
      for (int n = 0; n < FN; n++)
        acc[m][n] = __builtin_amdgcn_mfma_f32_16x16x32_bf16(av[m], bv[n], acc[m][n], 0, 0, 0);
    __builtin_amdgcn_s_setprio(0);

    if (kt + 1 < nt){
      if (kt + 3 < nt)      waitcnt_vm<8>();
      else if (kt + 2 < nt) waitcnt_vm<4>();
      else                  waitcnt_vm<0>();
      __builtin_amdgcn_s_barrier();
    }
  }

  __builtin_amdgcn_s_barrier();
  if (EPI == 1){
    u16* ep = (u16*)(lds + w*8192);   // 64x64 bf16 patch
#pragma unroll
    for (int n = 0; n < FN; n++){
      const float bvv = bias[bcol + wc + n*16 + fr];
#pragma unroll
      for (int m = 0; m < FM; m++)
#pragma unroll
        for (int r = 0; r < 4; r++)
          ep[(m*16 + fq*4 + r)*64 + n*16 + fr] = f2bf(fmaxf(acc[m][n][r] + bvv, 0.f));
    }
    asm volatile("s_waitcnt lgkmcnt(0)" ::: "memory");
    const int erow = l >> 3, ecb = (l & 7)*16;
#pragma unroll
    for (int it = 0; it < 8; it++){
      const int row = it*8 + erow;
      f32x4 v = *(const f32x4*)((const char*)ep + row*128 + ecb);
      char* gp = (char*)Cb + (((size_t)(brow + wr + row))*N + (bcol + wc))*2 + ecb;
      *(f32x4*)gp = v;
    }
  } else {
    float* ep = (float*)(lds + w*16384);  // 64x64 f32 patch
#pragma unroll
    for (int n = 0; n < FN; n++){
      const int gcol = bcol + wc + n*16 + fr;
      const float bvv = (gcol < ncols) ? bias[gcol] : 0.f;
#pragma unroll
      for (int m = 0; m < FM; m++)
#pragma unroll
        for (int r = 0; r < 4; r++)
          ep[(m*16 + fq*4 + r)*64 + n*16 + fr] = acc[m][n][r] + bvv;
    }
    asm volatile("s_waitcnt lgkmcnt(0)" ::: "memory");
    const int erow = l >> 4, ecb = (l & 15)*16;
    const int gcol0 = bcol + wc + (l & 15)*4;
#pragma unroll
    for (int it = 0; it < 16; it++){
      const int row = it*4 + erow;
      f32x4 v = *(const f32x4*)((const char*)ep + row*256 + ecb);
      if (gcol0 < ncols)
        *(f32x4*)(Cf + (size_t)(brow + wr + row)*ncols + gcol0) = v;
    }
  }
}

// ---- per-row: distances, argmin (exact fp64-refined candidates), softmax ----
__global__ __launch_bounds__(256)
void row_softmax(const u16* __restrict__ Sb, const float* __restrict__ x2,
                 const float* __restrict__ w2sq,
                 const float* __restrict__ x, const float* __restrict__ W,
                 u16* __restrict__ soft, float* __restrict__ winners)
{
  const int b = blockIdx.x, t = threadIdx.x;
  const float x2b = x2[b];
  const ushort4* S4 = (const ushort4*)(Sb + (size_t)b*4096);
  const f32x4* W24 = (const f32x4*)w2sq;
  float dv[16];
  float bd = 3.0e38f; int bc = 0;
#pragma unroll
  for (int i = 0; i < 4; i++){
    ushort4 s = S4[t + 256*i];
    f32x4 wv = W24[t + 256*i];
    float sf[4] = {bf2f(s.x), bf2f(s.y), bf2f(s.z), bf2f(s.w)};
#pragma unroll
    for (int j = 0; j < 4; j++){
      float u = x2b + wv[j];
      float d2 = u - 2.0f*sf[j];
      float d = __fsqrt_rn(fmaxf(d2, 1e-12f));
      dv[i*4 + j] = d;
      if (d < bd){ bd = d; bc = (t + 256*i)*4 + j; }
    }
  }
  u64 key = ((u64)__float_as_uint(bd) << 32) | (unsigned)bc;
#pragma unroll
  for (int s = 1; s < 64; s <<= 1){
    u64 o = __shfl_xor(key, s);
    if (o < key) key = o;
  }
  __shared__ u64 wk[4];
  __shared__ double csum[4];
  __shared__ float fred[4];
  __shared__ int ccnt;
  __shared__ int cand[32];
  if ((t & 63) == 0) wk[t >> 6] = key;
  if (t == 0) ccnt = 0;
  __syncthreads();
  u64 k0 = wk[0];
  if (wk[1] < k0) k0 = wk[1];
  if (wk[2] < k0) k0 = wk[2];
  if (wk[3] < k0) k0 = wk[3];
  const float dmin = __uint_as_float((unsigned)(k0 >> 32));

  const float thr = dmin + 0.01f;
#pragma unroll
  for (int i = 0; i < 4; i++)
#pragma unroll
    for (int j = 0; j < 4; j++)
      if (dv[i*4 + j] <= thr){
        int p = atomicAdd(&ccnt, 1);
        if (p < 32) cand[p] = (t + 256*i)*4 + j;
      }
  __syncthreads();
  const int nc = min(ccnt, 32);

  float bestd = 3.0e38f; int besti = 0x7fffffff;
  const f32x4* xp = (const f32x4*)(x + (size_t)b*2048) + t*2;
  f32x4 xv0 = xp[0], xv1 = xp[1];
  for (int c = 0; c < nc; c++){
    const int h = cand[c];
    const f32x4* wp = (const f32x4*)(W + (size_t)h*2048) + t*2;
    f32x4 wv0 = wp[0], wv1 = wp[1];
    double a = 0.0;
#pragma unroll
    for (int j = 0; j < 4; j++) a += (double)xv0[j]*(double)wv0[j];
#pragma unroll
    for (int j = 0; j < 4; j++) a += (double)xv1[j]*(double)wv1[j];
#pragma unroll
    for (int s = 1; s < 64; s <<= 1) a += __shfl_xor(a, s);
    if ((t & 63) == 0) csum[t >> 6] = a;
    __syncthreads();
    if (t == 0){
      double tt = (csum[0] + csum[1]) + (csum[2] + csum[3]);
      float t32 = (float)tt;
      float u = x2b + w2sq[h];
      float d2 = u - 2.0f*t32;
      float d = __fsqrt_rn(fmaxf(d2, 1e-12f));
      if (d < bestd || (d == bestd && h < besti)){ bestd = d; besti = h; }
    }
    __syncthreads();
  }
  if (t == 0) winners[b] = (float)besti;

  float es = 0.f;
#pragma unroll
  for (int i = 0; i < 16; i++) es += __expf(-2.0f*(dv[i] - dmin));
#pragma unroll
  for (int s = 1; s < 64; s <<= 1) es += __shfl_xor(es, s);
  if ((t & 63) == 0) fred[t >> 6] = es;
  __syncthreads();
  const float tot = (fred[0] + fred[1]) + (fred[2] + fred[3]);
  const float inv = 1.0f / tot;
  ushort4* o4 = (ushort4*)(soft + (size_t)b*4096);
#pragma unroll
  for (int i = 0; i < 4; i++){
    ushort4 o;
    o.x = f2bf(__expf(-2.0f*(dv[i*4+0] - dmin))*inv);
    o.y = f2bf(__expf(-2.0f*(dv[i*4+1] - dmin))*inv);
    o.z = f2bf(__expf(-2.0f*(dv[i*4+2] - dmin))*inv);
    o.w = f2bf(__expf(-2.0f*(dv[i*4+3] - dmin))*inv);
    o4[t + 256*i] = o;
  }
}

extern "C" void kernel_launch(void* const* d_in, const int* in_sizes, int n_in,
                              void* d_out, int out_size, void* d_ws, size_t ws_size,
                              hipStream_t stream)
{
  const float* x  = (const float*)d_in[0];
  const float* Wk = (const float*)d_in[1];
  const float* w1 = (const float*)d_in[2];
  const float* b1 = (const float*)d_in[3];
  const float* w2 = (const float*)d_in[4];
  const float* b2 = (const float*)d_in[5];
  const float* w3 = (const float*)d_in[6];
  const float* b3 = (const float*)d_in[7];
  float* out = (float*)d_out;
  float* winners = out + (size_t)4096*1000;

  char* ws = (char*)d_ws;
  const size_t MB = 1u << 20;
  u16* Sb    = (u16*)(ws);                // 32MB bf16 S [dead after row_softmax]
  u16* soft  = (u16*)(ws + 32*MB);        // 32MB
  u16* w1b   = (u16*)(ws + 64*MB);        // 16MB
  u16* w2b   = (u16*)(ws + 80*MB);        // 4MB
  u16* w3b   = (u16*)(ws + 84*MB);        // 2MB (padded 1024x1024)
  float* x2  = (float*)(ws + 86*MB);      // 16KB
  float* w2s = x2 + 4096;                 // 16KB
  u16* xb    = (u16*)(ws + 88*MB);        // 16MB [dead after gemm1]
  u16* wb    = (u16*)(ws + 104*MB);       // 16MB [dead after gemm1]
  u16* P0    = (u16*)(ws + 88*MB);        // 16MB splitK partial, overlays xb
  u16* P1    = (u16*)(ws + 104*MB);       // 16MB partial, overlays wb
  u16* h1    = (u16*)(ws);                // 16MB overlays Sb
  u16* h2    = (u16*)(ws + 16*MB);        // 8MB  overlays Sb

  cvt_rows<<<4096, 64, 0, stream>>>(x, xb, x2);
  cvt_rows<<<4096, 64, 0, stream>>>(Wk, wb, w2s);
  cvt_mat<<<2048, 256, 0, stream>>>(w1, w1b, 2048*4096/4);
  cvt_mat<<<1024, 256, 0, stream>>>(w2, w2b, 1024*2048/4);
  hipMemsetAsync(w3b, 0, (size_t)1024*1024*2, stream);
  cvt_mat<<<512, 256, 0, stream>>>(w3, w3b, 1000*1024/4);

  hipFuncSetAttribute((const void*)gemmA,
                      hipFuncAttributeMaxDynamicSharedMemorySize, 73728);

  // S = x @ W^T -> bf16  (256x128, grid 512 = 2 blocks/CU)
  gemmA<<<512, 256, 73728, stream>>>(xb, 2048, wb, 2048, Sb,
                                     4096, 2048, 32, 512);

  // distances -> winners (exact refine) + soft (bf16)
  row_softmax<<<4096, 256, 0, stream>>>(Sb, x2, w2s, x, Wk, soft, winners);

  // h1 = relu(soft @ w1^T + b1): split-K x2 (grid 512 = 2/CU) + combine
  gemmA<<<512, 256, 73728, stream>>>(soft, 4096, w1b, 4096, P0,
                                     2048, 2048, 16, 256);
  combine_relu<<<2048, 256, 0, stream>>>(P0, P1, b1, h1);

  // h2 = relu(h1 @ w2^T + b2)   (128^2 tile, 4 waves, 64KB LDS)
  hipFuncSetAttribute((const void*)gemm_p<128,128,2,2,1,3>,
                      hipFuncAttributeMaxDynamicSharedMemorySize, 4*256*64);
  gemm_p<128,128,2,2,1,3><<<256, 256, 4*256*64, stream>>>(
      h1, w2b, nullptr, h2, b2, 4096, 1024, 2048, 0, 8);

  // out = h2 @ w3^T + b3  (fp32, 1000 valid cols)
  hipFuncSetAttribute((const void*)gemm_p<128,128,2,2,2,3>,
                      hipFuncAttributeMaxDynamicSharedMemorySize, 4*256*64);
  gemm_p<128,128,2,2,2,3><<<256, 256, 4*256*64, stream>>>(
      h2, w3b, out, nullptr, b3, 4096, 1024, 1024, 1000, 8);
}

// Round 8
// 250.978 us; speedup vs baseline: 1.1267x; 1.1267x over previous
//
#include <hip/hip_runtime.h>
#include <hip/hip_bf16.h>
#include <stdint.h>

typedef __attribute__((ext_vector_type(4))) float f32x4;
typedef __attribute__((ext_vector_type(8))) __bf16 bf16x8;
typedef unsigned short u16;
typedef unsigned long long u64;

__device__ __forceinline__ u16 f2bf(float f){
  unsigned u = __float_as_uint(f);
  u += 0x7fffu + ((u >> 16) & 1u);
  return (u16)(u >> 16);
}
__device__ __forceinline__ float bf2f(u16 v){
  return __uint_as_float(((unsigned)v) << 16);
}

__device__ __forceinline__ void gload16(const u16* g, u16* l){
  __builtin_amdgcn_global_load_lds(
      (__attribute__((address_space(1))) void*)g,
      (__attribute__((address_space(3))) void*)l, 16, 0, 0);
}

template<int N> __device__ __forceinline__ void waitcnt_vm(){
  if constexpr (N==0)  asm volatile("s_waitcnt vmcnt(0)" ::: "memory");
  else if constexpr (N==4)  asm volatile("s_waitcnt vmcnt(4)" ::: "memory");
  else if constexpr (N==8)  asm volatile("s_waitcnt vmcnt(8)" ::: "memory");
}

// ---- fused: fp32 rows -> bf16 + numpy-pairwise row sum-of-squares ----
// blocks 0..4095 process x, 4096..8191 process Wk.
__global__ __launch_bounds__(64)
void cvt_rows2(const float* __restrict__ x, const float* __restrict__ Wk,
               u16* __restrict__ xb, u16* __restrict__ wb,
               float* __restrict__ x2, float* __restrict__ w2s)
{
#pragma clang fp contract(off)
  const int bid = blockIdx.x;
  const int row = bid & 4095;
  const float* src = (bid < 4096) ? x : Wk;
  u16* dst = (bid < 4096) ? xb : wb;
  float* sq = (bid < 4096) ? x2 : w2s;
  const int l = threadIdx.x;
  const float* r = src + (size_t)row * 2048;
  const f32x4* r4 = (const f32x4*)r;
  ushort4* d4 = (ushort4*)(dst + (size_t)row * 2048);
#pragma unroll
  for (int i = 0; i < 8; i++){
    f32x4 v = r4[l + 64*i];
    ushort4 o;
    o.x = f2bf(v.x); o.y = f2bf(v.y); o.z = f2bf(v.z); o.w = f2bf(v.w);
    d4[l + 64*i] = o;
  }
  float leaf = 0.f;
  if (l < 16){
    const f32x4* p4 = (const f32x4*)(r + l*128);
    f32x4 a0 = {0.f,0.f,0.f,0.f}, a1 = {0.f,0.f,0.f,0.f};
#pragma unroll
    for (int i = 0; i < 32; i += 2){
      f32x4 v0 = p4[i], v1 = p4[i+1];
      a0 = a0 + v0*v0;
      a1 = a1 + v1*v1;
    }
    leaf = ((a0.x+a0.y)+(a0.z+a0.w))+((a1.x+a1.y)+(a1.z+a1.w));
  }
#pragma unroll
  for (int s = 1; s < 16; s <<= 1){
    float o = __shfl_down(leaf, s);
    if ((l & (2*s - 1)) == 0) leaf = leaf + o;
  }
  if (l == 0) sq[row] = leaf;
}

// ---- fused fp32 -> bf16 for w1, w2, w3 (w3 zero-padded 1024x1024) ----
__global__ __launch_bounds__(256)
void cvt_w(const float* __restrict__ w1, const float* __restrict__ w2,
           const float* __restrict__ w3,
           u16* __restrict__ w1b, u16* __restrict__ w2b, u16* __restrict__ w3b)
{
  const int N1 = 2097152;            // w1: 2048*4096/4
  const int N2 = N1 + 524288;        // w2: 1024*2048/4
  const int N3 = N2 + 262144;        // w3 dst: 1024*1024/4
  for (int i = blockIdx.x*256 + threadIdx.x; i < N3; i += gridDim.x*256){
    f32x4 v;
    ushort4* dp;
    if (i < N1){
      v = ((const f32x4*)w1)[i];
      dp = (ushort4*)w1b + i;
    } else if (i < N2){
      v = ((const f32x4*)w2)[i - N1];
      dp = (ushort4*)w2b + (i - N1);
    } else {
      const int j = i - N2;
      const int row = j >> 8;            // 256 f4 per 1024-col row
      const int col4 = (j & 255)*4;
      if (row < 1000) v = *(const f32x4*)(w3 + (size_t)row*1024 + col4);
      else            v = f32x4{0.f,0.f,0.f,0.f};
      dp = (ushort4*)w3b + j;
    }
    ushort4 o;
    o.x = f2bf(v.x); o.y = f2bf(v.y); o.z = f2bf(v.z); o.w = f2bf(v.w);
    *dp = o;
  }
}

// ==== gemmN: 256x256 BK=64 bf16 GEMM, A3/B2 LDS buffering, 1 barrier/tile ====
// 512 thr (8 waves 2Mx4N, wave 128x64). LDS = 3x32KB A + 2x32KB B = 160KB.
// Per tile t: read av0/bv0 | stage B(t+1) | sched_barrier(0) | 32 MFMA ks0 |
//   read av1/bv1 | stage A(t+2) | 32 MFMA ks1 | vmcnt(4) | s_barrier.
// Overwrite safety (rendezvous-only, no latency assumptions):
//  - A(t+2) -> Abuf[(t+2)%3] held A(t-1): all reads of A(t-1) were delivered
//    before each wave's last MFMA of tile t-1, hence before its arrival at
//    end-barrier(t-1); A(t+2) is issued only after crossing end-barrier(t-1).
//    Likewise A(t+3) (issued in t+1, after end-barrier(t)) vs reads of A(t).
//  - B(t+1) -> Bbuf[(t+1)&1] held B(t-1): same rendezvous at end-barrier(t-1).
// vmcnt ledger (issue order pinned: B(t+1) before A(t+2) via sched_barrier):
//   outstanding at end of t = A(t+1)[4, issued t-1] + B(t+1)[4] + A(t+2)[4];
//   vmcnt(4) waits the 8 oldest => tile t+1 fully landed; barrier publishes.
// Epilogue: per-wave 128x68-u16 LDS patch (136B stride, conflict-free),
// 16B coalesced stores. Split-K piece = wg/blkpp writes to Cb + piece*M*N.
__global__ __launch_bounds__(512, 1)
void gemmN(const u16* __restrict__ A, int lda,
           const u16* __restrict__ Bm, int ldb,
           u16* __restrict__ Cb, int N, int Kpp, int nbn, int blkpp)
{
  extern __shared__ char lds[];
  const int t = threadIdx.x;
  const int nwg = gridDim.x;
  const int cpx = nwg >> 3;
  const int bid = blockIdx.x;
  const int wg  = (bid & 7)*cpx + (bid >> 3);   // XCD swizzle (nwg%8==0)
  const int piece = wg / blkpp;
  const int rem = wg % blkpp;
  const int bm = rem / nbn, bn = rem % nbn;
  const int brow = bm*256, bcol = bn*256;
  const u16* Ab = A + (size_t)brow*lda + (size_t)piece*Kpp;
  const u16* Bb = Bm + (size_t)bcol*ldb + (size_t)piece*Kpp;
  u16* Cp = Cb + (size_t)piece * 4096 * N;

  const int l = t & 63, w = t >> 6;
  const int wm = w >> 2, wn = w & 3;
  const int wr = wm*128, wc = wn*64;
  const int fr = l & 15, fq = l >> 4;
  const int cb0 = (fq ^ (fr & 7)) << 4;          // ks0 chunk byte (swz)
  const int cb1 = ((4 + fq) ^ (fr & 7)) << 4;    // ks1 chunk byte (swz)
  const int scol8 = ((t & 7) ^ ((t >> 3) & 7)) * 8;  // inverse-swz src col
  const int srow = t >> 3;                       // 0..63 per round

  const int nt = Kpp >> 6;
  f32x4 acc[8][4] = {};

  auto stageA = [&](int kt, int buf){
    const u16* s0 = Ab + (size_t)srow*lda + kt*64 + scol8;
    char* d = lds + buf*32768 + t*16;
#pragma unroll
    for (int r = 0; r < 4; r++)
      gload16(s0 + (size_t)r*64*lda, (u16*)(d + r*8192));
  };
  auto stageB = [&](int kt){
    const u16* s0 = Bb + (size_t)srow*ldb + kt*64 + scol8;
    char* d = lds + 98304 + (kt & 1)*32768 + t*16;
#pragma unroll
    for (int r = 0; r < 4; r++)
      gload16(s0 + (size_t)r*64*ldb, (u16*)(d + r*8192));
  };
  auto ldA = [&](int buf, int m, int cb)->bf16x8 {
    return *(const bf16x8*)(lds + buf*32768 + (wr + m*16 + fr)*128 + cb);
  };
  auto ldB = [&](int kt, int n, int cb)->bf16x8 {
    return *(const bf16x8*)(lds + 98304 + (kt & 1)*32768 + (wc + n*16 + fr)*128 + cb);
  };

  // prologue: A0 -> buf0, B0; pin order; A1 -> buf1; wait A0,B0 (leave A1)
  stageA(0, 0); stageB(0);
  __builtin_amdgcn_sched_barrier(0);
  stageA(1, 1);
  waitcnt_vm<4>();
  __builtin_amdgcn_s_barrier();

  int ra = 0, sa = 2;   // read-buf of tile kt, stage-buf of tile kt+2
  for (int kt = 0; kt < nt; kt++){
    bf16x8 av0[8], av1[8], bv0[4], bv1[4];

#pragma unroll
    for (int m = 0; m < 8; m++) av0[m] = ldA(ra, m, cb0);
#pragma unroll
    for (int n = 0; n < 4; n++) bv0[n] = ldB(kt, n, cb0);
    if (kt + 1 < nt) stageB(kt + 1);
    __builtin_amdgcn_sched_barrier(0);   // pin: B(t+1) issues before A(t+2)
    __builtin_amdgcn_s_setprio(1);
#pragma unroll
    for (int m = 0; m < 8; m++)
#pragma unroll
      for (int n = 0; n < 4; n++)
        acc[m][n] = __builtin_amdgcn_mfma_f32_16x16x32_bf16(av0[m], bv0[n], acc[m][n], 0, 0, 0);
    __builtin_amdgcn_s_setprio(0);

#pragma unroll
    for (int m = 0; m < 8; m++) av1[m] = ldA(ra, m, cb1);
#pragma unroll
    for (int n = 0; n < 4; n++) bv1[n] = ldB(kt, n, cb1);
    if (kt + 2 < nt) stageA(kt + 2, sa);
    __builtin_amdgcn_s_setprio(1);
#pragma unroll
    for (int m = 0; m < 8; m++)
#pragma unroll
      for (int n = 0; n < 4; n++)
        acc[m][n] = __builtin_amdgcn_mfma_f32_16x16x32_bf16(av1[m], bv1[n], acc[m][n], 0, 0, 0);
    __builtin_amdgcn_s_setprio(0);

    if (kt + 1 < nt){
      if (kt + 2 < nt) waitcnt_vm<4>();
      else             waitcnt_vm<0>();
      __builtin_amdgcn_s_barrier();
    }
    ra = (ra == 2) ? 0 : ra + 1;
    sa = (sa == 2) ? 0 : sa + 1;
  }

  // ---- epilogue: 136B-stride LDS patch (conflict-free), coalesced stores ----
  __builtin_amdgcn_s_barrier();        // all K-loop LDS reads delivered
  u16* ep = (u16*)(lds + w*17408);     // 128 rows x 68 u16
#pragma unroll
  for (int m = 0; m < 8; m++)
#pragma unroll
    for (int n = 0; n < 4; n++)
#pragma unroll
      for (int r = 0; r < 4; r++)
        ep[(m*16 + fq*4 + r)*68 + n*16 + fr] = f2bf(acc[m][n][r]);
  asm volatile("s_waitcnt lgkmcnt(0)" ::: "memory");
  const int erow = l >> 3, ecb = (l & 7)*16;
#pragma unroll
  for (int it = 0; it < 16; it++){
    const int row = it*8 + erow;
    f32x4 v = *(const f32x4*)((const char*)ep + row*136 + ecb);
    char* gp = (char*)Cp + (((size_t)(brow + wr + row))*N + (bcol + wc))*2 + ecb;
    *(f32x4*)gp = v;
  }
}

// ---- combine split-K partials + bias + relu -> bf16 ----
__global__ __launch_bounds__(256)
void combine_relu(const u16* __restrict__ p0, const u16* __restrict__ p1,
                  const float* __restrict__ bias, u16* __restrict__ out)
{
  const int n4 = 4096*2048/4;
  for (int i = blockIdx.x*256 + threadIdx.x; i < n4; i += gridDim.x*256){
    ushort4 a = ((const ushort4*)p0)[i];
    ushort4 b = ((const ushort4*)p1)[i];
    const int col = (i*4) & 2047;
    f32x4 bi = *(const f32x4*)(bias + col);
    ushort4 o;
    o.x = f2bf(fmaxf(bf2f(a.x) + bf2f(b.x) + bi.x, 0.f));
    o.y = f2bf(fmaxf(bf2f(a.y) + bf2f(b.y) + bi.y, 0.f));
    o.z = f2bf(fmaxf(bf2f(a.z) + bf2f(b.z) + bi.z, 0.f));
    o.w = f2bf(fmaxf(bf2f(a.w) + bf2f(b.w) + bi.w, 0.f));
    ((ushort4*)out)[i] = o;
  }
}

// ---- small-GEMM pipeline (G3/G4): 1 barrier per K-tile + LDS epilogue ----
template<int BM, int BN, int WM, int WN, int EPI, int MINW>
__global__ __launch_bounds__(WM*WN*64, MINW)
void gemm_p(const u16* __restrict__ A, const u16* __restrict__ Bm,
            float* __restrict__ Cf, u16* __restrict__ Cb,
            const float* __restrict__ bias,
            int M, int N, int K, int ncols, int nbn)
{
  constexpr int T  = WM*WN*64;
  constexpr int FM = BM/(WM*16);
  constexpr int FN = BN/(WN*16);
  constexpr int ABYTES = BM*64;
  constexpr int BUFB   = (BM+BN)*64;
  constexpr int RA = ABYTES/(T*16);
  constexpr int RB = (BN*64)/(T*16);
  extern __shared__ char lds[];

  const int t = threadIdx.x;
  const int nwg = gridDim.x;
  const int cpx = nwg >> 3;
  const int bid = blockIdx.x;
  const int wg  = (bid & 7)*cpx + (bid >> 3);
  const int bm = wg / nbn, bn = wg % nbn;
  const int brow = bm*BM, bcol = bn*BN;

  const int l = t & 63, w = t >> 6;
  const int wm = w / WN, wn = w % WN;
  const int wr = wm*(FM*16), wc = wn*(FN*16);
  const int fr = l & 15, fq = l >> 4, fk = fq*8;
  const int xk = fk ^ (((fr >> 1) & 3) << 3);

  const int srow = t >> 2;
  const int scol = ((t & 3)*8) ^ (((t >> 3) & 3) << 3);

  const u16* agp[RA]; const u16* bgp[RB];
#pragma unroll
  for (int r = 0; r < RA; r++)
    agp[r] = A + (size_t)(brow + r*(T>>2) + srow)*K + scol;
#pragma unroll
  for (int r = 0; r < RB; r++)
    bgp[r] = Bm + (size_t)(bcol + r*(T>>2) + srow)*K + scol;

  f32x4 acc[FM][FN] = {};
  const int nt = K >> 5;

  auto stageA = [&](int kt, int buf){
    char* dst = lds + buf*BUFB + t*16;
#pragma unroll
    for (int r = 0; r < RA; r++)
      gload16(agp[r] + (kt << 5), (u16*)(dst + r*T*16));
  };
  auto stageB = [&](int kt, int buf){
    char* dst = lds + buf*BUFB + ABYTES + t*16;
#pragma unroll
    for (int r = 0; r < RB; r++)
      gload16(bgp[r] + (kt << 5), (u16*)(dst + r*T*16));
  };

  stageA(0, 0); stageB(0, 0);
  stageA(1, 1); stageB(1, 1);
  stageA(2, 2); stageB(2, 2);
  waitcnt_vm<8>();
  __builtin_amdgcn_s_barrier();

  for (int kt = 0; kt < nt; kt++){
    const int buf = kt & 3;
    const u16* As = (const u16*)(lds + buf*BUFB);
    const u16* Bs = (const u16*)(lds + buf*BUFB + ABYTES);
    const bool pre = (kt + 3 < nt);
    const int nbuf = (kt + 3) & 3;

    bf16x8 av[FM], bv[FN];
#pragma unroll
    for (int m = 0; m < FM; m++)
      av[m] = *(const bf16x8*)(As + (wr + m*16 + fr)*32 + xk);
#pragma unroll
    for (int n = 0; n < FN; n++)
      bv[n] = *(const bf16x8*)(Bs + (wc + n*16 + fr)*32 + xk);
    if (pre){ stageA(kt + 3, nbuf); stageB(kt + 3, nbuf); }
    __builtin_amdgcn_s_setprio(1);
#pragma unroll
    for (int m = 0; m < FM; m++)
#pragma unroll
      for (int n = 0; n < FN; n++)
        acc[m][n] = __builtin_amdgcn_mfma_f32_16x16x32_bf16(av[m], bv[n], acc[m][n], 0, 0, 0);
    __builtin_amdgcn_s_setprio(0);

    if (kt + 1 < nt){
      if (kt + 3 < nt)      waitcnt_vm<8>();
      else if (kt + 2 < nt) waitcnt_vm<4>();
      else                  waitcnt_vm<0>();
      __builtin_amdgcn_s_barrier();
    }
  }

  __builtin_amdgcn_s_barrier();
  if (EPI == 1){
    u16* ep = (u16*)(lds + w*8192);   // 64x64 bf16 patch
#pragma unroll
    for (int n = 0; n < FN; n++){
      const float bvv = bias[bcol + wc + n*16 + fr];
#pragma unroll
      for (int m = 0; m < FM; m++)
#pragma unroll
        for (int r = 0; r < 4; r++)
          ep[(m*16 + fq*4 + r)*64 + n*16 + fr] = f2bf(fmaxf(acc[m][n][r] + bvv, 0.f));
    }
    asm volatile("s_waitcnt lgkmcnt(0)" ::: "memory");
    const int erow = l >> 3, ecb = (l & 7)*16;
#pragma unroll
    for (int it = 0; it < 8; it++){
      const int row = it*8 + erow;
      f32x4 v = *(const f32x4*)((const char*)ep + row*128 + ecb);
      char* gp = (char*)Cb + (((size_t)(brow + wr + row))*N + (bcol + wc))*2 + ecb;
      *(f32x4*)gp = v;
    }
  } else {
    float* ep = (float*)(lds + w*16384);  // 64x64 f32 patch
#pragma unroll
    for (int n = 0; n < FN; n++){
      const int gcol = bcol + wc + n*16 + fr;
      const float bvv = (gcol < ncols) ? bias[gcol] : 0.f;
#pragma unroll
      for (int m = 0; m < FM; m++)
#pragma unroll
        for (int r = 0; r < 4; r++)
          ep[(m*16 + fq*4 + r)*64 + n*16 + fr] = acc[m][n][r] + bvv;
    }
    asm volatile("s_waitcnt lgkmcnt(0)" ::: "memory");
    const int erow = l >> 4, ecb = (l & 15)*16;
    const int gcol0 = bcol + wc + (l & 15)*4;
#pragma unroll
    for (int it = 0; it < 16; it++){
      const int row = it*4 + erow;
      f32x4 v = *(const f32x4*)((const char*)ep + row*256 + ecb);
      if (gcol0 < ncols)
        *(f32x4*)(Cf + (size_t)(brow + wr + row)*ncols + gcol0) = v;
    }
  }
}

// ---- per-row: distances, argmin (exact fp64-refined candidates), softmax ----
__global__ __launch_bounds__(256)
void row_softmax(const u16* __restrict__ Sb, const float* __restrict__ x2,
                 const float* __restrict__ w2sq,
                 const float* __restrict__ x, const float* __restrict__ W,
                 u16* __restrict__ soft, float* __restrict__ winners)
{
  const int b = blockIdx.x, t = threadIdx.x;
  const float x2b = x2[b];
  const ushort4* S4 = (const ushort4*)(Sb + (size_t)b*4096);
  const f32x4* W24 = (const f32x4*)w2sq;
  float dv[16];
  float bd = 3.0e38f; int bc = 0;
#pragma unroll
  for (int i = 0; i < 4; i++){
    ushort4 s = S4[t + 256*i];
    f32x4 wv = W24[t + 256*i];
    float sf[4] = {bf2f(s.x), bf2f(s.y), bf2f(s.z), bf2f(s.w)};
#pragma unroll
    for (int j = 0; j < 4; j++){
      float u = x2b + wv[j];
      float d2 = u - 2.0f*sf[j];
      float d = __fsqrt_rn(fmaxf(d2, 1e-12f));
      dv[i*4 + j] = d;
      if (d < bd){ bd = d; bc = (t + 256*i)*4 + j; }
    }
  }
  u64 key = ((u64)__float_as_uint(bd) << 32) | (unsigned)bc;
#pragma unroll
  for (int s = 1; s < 64; s <<= 1){
    u64 o = __shfl_xor(key, s);
    if (o < key) key = o;
  }
  __shared__ u64 wk[4];
  __shared__ double csum[4];
  __shared__ float fred[4];
  __shared__ int ccnt;
  __shared__ int cand[32];
  if ((t & 63) == 0) wk[t >> 6] = key;
  if (t == 0) ccnt = 0;
  __syncthreads();
  u64 k0 = wk[0];
  if (wk[1] < k0) k0 = wk[1];
  if (wk[2] < k0) k0 = wk[2];
  if (wk[3] < k0) k0 = wk[3];
  const float dmin = __uint_as_float((unsigned)(k0 >> 32));

  const float thr = dmin + 0.01f;
#pragma unroll
  for (int i = 0; i < 4; i++)
#pragma unroll
    for (int j = 0; j < 4; j++)
      if (dv[i*4 + j] <= thr){
        int p = atomicAdd(&ccnt, 1);
        if (p < 32) cand[p] = (t + 256*i)*4 + j;
      }
  __syncthreads();
  const int nc = min(ccnt, 32);

  float bestd = 3.0e38f; int besti = 0x7fffffff;
  const f32x4* xp = (const f32x4*)(x + (size_t)b*2048) + t*2;
  f32x4 xv0 = xp[0], xv1 = xp[1];
  for (int c = 0; c < nc; c++){
    const int h = cand[c];
    const f32x4* wp = (const f32x4*)(W + (size_t)h*2048) + t*2;
    f32x4 wv0 = wp[0], wv1 = wp[1];
    double a = 0.0;
#pragma unroll
    for (int j = 0; j < 4; j++) a += (double)xv0[j]*(double)wv0[j];
#pragma unroll
    for (int j = 0; j < 4; j++) a += (double)xv1[j]*(double)wv1[j];
#pragma unroll
    for (int s = 1; s < 64; s <<= 1) a += __shfl_xor(a, s);
    if ((t & 63) == 0) csum[t >> 6] = a;
    __syncthreads();
    if (t == 0){
      double tt = (csum[0] + csum[1]) + (csum[2] + csum[3]);
      float t32 = (float)tt;
      float u = x2b + w2sq[h];
      float d2 = u - 2.0f*t32;
      float d = __fsqrt_rn(fmaxf(d2, 1e-12f));
      if (d < bestd || (d == bestd && h < besti)){ bestd = d; besti = h; }
    }
    __syncthreads();
  }
  if (t == 0) winners[b] = (float)besti;

  float es = 0.f;
#pragma unroll
  for (int i = 0; i < 16; i++) es += __expf(-2.0f*(dv[i] - dmin));
#pragma unroll
  for (int s = 1; s < 64; s <<= 1) es += __shfl_xor(es, s);
  if ((t & 63) == 0) fred[t >> 6] = es;
  __syncthreads();
  const float tot = (fred[0] + fred[1]) + (fred[2] + fred[3]);
  const float inv = 1.0f / tot;
  ushort4* o4 = (ushort4*)(soft + (size_t)b*4096);
#pragma unroll
  for (int i = 0; i < 4; i++){
    ushort4 o;
    o.x = f2bf(__expf(-2.0f*(dv[i*4+0] - dmin))*inv);
    o.y = f2bf(__expf(-2.0f*(dv[i*4+1] - dmin))*inv);
    o.z = f2bf(__expf(-2.0f*(dv[i*4+2] - dmin))*inv);
    o.w = f2bf(__expf(-2.0f*(dv[i*4+3] - dmin))*inv);
    o4[t + 256*i] = o;
  }
}

extern "C" void kernel_launch(void* const* d_in, const int* in_sizes, int n_in,
                              void* d_out, int out_size, void* d_ws, size_t ws_size,
                              hipStream_t stream)
{
  const float* x  = (const float*)d_in[0];
  const float* Wk = (const float*)d_in[1];
  const float* w1 = (const float*)d_in[2];
  const float* b1 = (const float*)d_in[3];
  const float* w2 = (const float*)d_in[4];
  const float* b2 = (const float*)d_in[5];
  const float* w3 = (const float*)d_in[6];
  const float* b3 = (const float*)d_in[7];
  float* out = (float*)d_out;
  float* winners = out + (size_t)4096*1000;

  char* ws = (char*)d_ws;
  const size_t MB = 1u << 20;
  u16* Sb    = (u16*)(ws);                // 32MB bf16 S [dead after row_softmax]
  u16* soft  = (u16*)(ws + 32*MB);        // 32MB
  u16* w1b   = (u16*)(ws + 64*MB);        // 16MB
  u16* w2b   = (u16*)(ws + 80*MB);        // 4MB
  u16* w3b   = (u16*)(ws + 84*MB);        // 2MB (padded 1024x1024)
  float* x2  = (float*)(ws + 86*MB);      // 16KB
  float* w2s = x2 + 4096;                 // 16KB
  u16* xb    = (u16*)(ws + 88*MB);        // 16MB [dead after gemm1]
  u16* wb    = (u16*)(ws + 104*MB);       // 16MB [dead after gemm1]
  u16* P0    = (u16*)(ws + 88*MB);        // 16MB splitK partial, overlays xb
  u16* P1    = (u16*)(ws + 104*MB);       // 16MB partial, overlays wb
  u16* h1    = (u16*)(ws);                // 16MB overlays Sb
  u16* h2    = (u16*)(ws + 16*MB);        // 8MB  overlays Sb

  cvt_rows2<<<8192, 64, 0, stream>>>(x, Wk, xb, wb, x2, w2s);
  cvt_w<<<2048, 256, 0, stream>>>(w1, w2, w3, w1b, w2b, w3b);

  hipFuncSetAttribute((const void*)gemmN,
                      hipFuncAttributeMaxDynamicSharedMemorySize, 163840);

  // S = x @ W^T -> bf16  (256^2, A3/B2, 1 barrier/tile)
  gemmN<<<256, 512, 163840, stream>>>(xb, 2048, wb, 2048, Sb,
                                      4096, 2048, 16, 256);

  // distances -> winners (exact refine) + soft (bf16)
  row_softmax<<<4096, 256, 0, stream>>>(Sb, x2, w2s, x, Wk, soft, winners);

  // h1 = relu(soft @ w1^T + b1): split-K x2 + combine
  gemmN<<<256, 512, 163840, stream>>>(soft, 4096, w1b, 4096, P0,
                                      2048, 2048, 8, 128);
  combine_relu<<<2048, 256, 0, stream>>>(P0, P1, b1, h1);

  // h2 = relu(h1 @ w2^T + b2)   (128^2 tile, 4 waves, 64KB LDS)
  hipFuncSetAttribute((const void*)gemm_p<128,128,2,2,1,3>,
                      hipFuncAttributeMaxDynamicSharedMemorySize, 4*256*64);
  gemm_p<128,128,2,2,1,3><<<256, 256, 4*256*64, stream>>>(
      h1, w2b, nullptr, h2, b2, 4096, 1024, 2048, 0, 8);

  // out = h2 @ w3^T + b3  (fp32, 1000 valid cols)
  hipFuncSetAttribute((const void*)gemm_p<128,128,2,2,2,3>,
                      hipFuncAttributeMaxDynamicSharedMemorySize, 4*256*64);
  gemm_p<128,128,2,2,2,3><<<256, 256, 4*256*64, stream>>>(
      h2, w3b, out, nullptr, b3, 4096, 1024, 1024, 1000, 8);
}